// Round 5
// baseline (17209.814 us; speedup 1.0000x reference)
//
#include <hip/hip_runtime.h>
#include <stdint.h>

#define NCU 256
#define TPB 512
#define IN_DIM 1024
#define HID1   1024
#define HID2   2048
#define T_STEPS 2048

// Exchange geometry: per (buffer, source) there are NCOPY replicated 128-byte
// lines. A line = 16 pairs {payload dword, tag dword}; pairs 0..3 = h1 units,
// pairs 4..11 = h2 units, 12..15 pad. Consumer block b polls copy (b>>4) ->
// only 16 reader blocks per address (vs 256 in round 3/4).
#define NCOPY 16
#define LINE_DW 32   // 128 B, 128-B aligned

typedef float    f32x4 __attribute__((ext_vector_type(4)));
typedef uint32_t u32x4 __attribute__((ext_vector_type(4)));
typedef uint32_t u32x2 __attribute__((ext_vector_type(2)));

__device__ __forceinline__ float bf_lo(uint32_t u){ return __uint_as_float(u << 16); }
__device__ __forceinline__ float bf_hi(uint32_t u){ return __uint_as_float(u & 0xffff0000u); }
__device__ __forceinline__ uint32_t f2bf(float f){
  uint32_t x = __float_as_uint(f);
  return (x + 0x7fffu + ((x >> 16) & 1u)) >> 16;   // RNE
}
__device__ __forceinline__ uint32_t pack2(float a, float b){
  return f2bf(a) | (f2bf(b) << 16);
}
__device__ __forceinline__ float wave_reduce(float v){
  v += __shfl_xor(v, 32); v += __shfl_xor(v, 16); v += __shfl_xor(v, 8);
  v += __shfl_xor(v, 4);  v += __shfl_xor(v, 2);  v += __shfl_xor(v, 1);
  return v;
}
__device__ __forceinline__ float sigmoidf_(float x){ return 1.0f / (1.0f + expf(-x)); }

__global__ void prep_kernel(uint32_t* __restrict__ combined)
{
  int idx = blockIdx.x * blockDim.x + threadIdx.x;
  const int total = 4 * NCU * NCOPY * LINE_DW;
  for (int i = idx; i < total; i += gridDim.x * blockDim.x)
    __hip_atomic_store(combined + i, 0u, __ATOMIC_RELAXED, __HIP_MEMORY_SCOPE_AGENT);
}

// ---------------------------------------------------------------------------
// persistent 2-layer LSTM scan. 256 blocks (1/CU) x 512 threads.
// Block b owns layer1 units [4b,4b+4) and layer2 units [8b,8b+8).
// Iteration t computes h1[t] (phase A, needs h1[t-1]) and h2[t-2]
// (phase B, needs h1[t-2], h2[t-3]).
// ---------------------------------------------------------------------------
__global__ __launch_bounds__(TPB, 1) void lstm_persist(
    const float* __restrict__ x,    const float* __restrict__ Wih1,
    const float* __restrict__ Whh1, const float* __restrict__ b1,
    const float* __restrict__ Wih2, const float* __restrict__ Whh2,
    const float* __restrict__ b2,   const float* __restrict__ Wout,
    uint32_t* __restrict__ combined, float* __restrict__ partial_out)
{
  __shared__ u32x4 whh2_u4[32 * 256];    // 128 KiB bf16 Whh2 slice
  __shared__ f32x4 h1buf[2][HID1 / 4];   // double-buffered h1 (2 x 4 KiB)
  __shared__ f32x4 h2_4[HID2 / 4];       // h2[t-3] (8 KiB)
  __shared__ float gsum1[16], gx1v[16], gsum2[32], b2v[32];

  const int b    = blockIdx.x;
  const int tid  = threadIdx.x;
  const int lane = tid & 63;
  const int wv   = tid >> 6;   // 8 waves

  // ---- init: stage Whh2 slice into LDS (fp32 -> bf16, paired-block layout) --
  for (int i = tid; i < 32 * 256; i += TPB) {
    int lr = i >> 8, u = i & 255;
    int g = lr >> 3, uu2 = lr & 7;
    const f32x4* s4 = (const f32x4*)(Whh2 + (int64_t)(g * HID2 + 8 * b + uu2) * HID2);
    f32x4 lo = s4[u], hi = s4[256 + u];
    u32x4 wv4;
    wv4[0] = pack2(lo[0], lo[1]); wv4[1] = pack2(lo[2], lo[3]);
    wv4[2] = pack2(hi[0], hi[1]); wv4[3] = pack2(hi[2], hi[3]);
    whh2_u4[i] = wv4;
  }

  // ---- Whh1 slice in registers (fp32, 2 rows/wave, 16 elems/lane/row) ----
  float w1r[2][16];
  int rows1[2];
  #pragma unroll
  for (int rr = 0; rr < 2; ++rr) {
    int lr1 = wv * 2 + rr;
    int g = lr1 >> 2, uu = lr1 & 3;
    int row = g * HID1 + 4 * b + uu;
    rows1[rr] = row;
    #pragma unroll
    for (int j = 0; j < 16; ++j)
      w1r[rr][j] = Whh1[(int64_t)row * IN_DIM + lane + 64 * j];
  }

  // ---- Wih2 slice in registers (bf16 packed, paired-block layout) ----
  u32x4 wi_reg[4][2];
  #pragma unroll
  for (int rr = 0; rr < 4; ++rr) {
    int lr = wv * 4 + rr;
    int g = lr >> 3, uu = lr & 7;
    const f32x4* s4 = (const f32x4*)(Wih2 + (int64_t)(g * HID2 + 8 * b + uu) * IN_DIM);
    #pragma unroll
    for (int q = 0; q < 2; ++q) {
      int u = lane + 64 * q;
      f32x4 lo = s4[u], hi = s4[128 + u];
      u32x4 wv4;
      wv4[0] = pack2(lo[0], lo[1]); wv4[1] = pack2(lo[2], lo[3]);
      wv4[2] = pack2(hi[0], hi[1]); wv4[3] = pack2(hi[2], hi[3]);
      wi_reg[rr][q] = wv4;
    }
  }

  // ---- gx1 = Wih1 @ x + b1 (constant over t) ----
  #pragma unroll
  for (int rr = 0; rr < 2; ++rr) {
    int row = rows1[rr];
    float s = 0.f;
    #pragma unroll
    for (int j = 0; j < 16; ++j)
      s += Wih1[(int64_t)row * IN_DIM + lane + 64 * j] * x[lane + 64 * j];
    s = wave_reduce(s);
    if (lane == 0) gx1v[wv * 2 + rr] = s + b1[row];
  }
  if (tid < 32) { int g = tid >> 3, uu = tid & 7; b2v[tid] = b2[g * HID2 + 8 * b + uu]; }
  {
    float* h1a = (float*)h1buf[0];
    float* h1bb = (float*)h1buf[1];
    float* h2a = (float*)h2_4;
    for (int i = tid; i < HID1; i += TPB) { h1a[i] = 0.f; h1bb[i] = 0.f; }
    for (int i = tid; i < HID2; i += TPB) h2a[i] = 0.f;
  }

  const float woutreg = Wout[8 * b + (lane & 7)];
  float c1reg = 0.f, c2reg = 0.f;
  __syncthreads();

  // ---- time loop ----
  for (int t = 0; t < T_STEPS + 2; ++t) {
    if (t < T_STEPS) {
      // Phase A: layer1 recurrent matvec over h1[t-1]
      const float* h1A = (const float*)h1buf[(t + 1) & 1];
      #pragma unroll
      for (int rr = 0; rr < 2; ++rr) {
        float s = 0.f;
        #pragma unroll
        for (int j = 0; j < 16; ++j) s += w1r[rr][j] * h1A[lane + 64 * j];
        s = wave_reduce(s);
        if (lane == 0) gsum1[wv * 2 + rr] = s;
      }
    }
    if (t >= 2) {
      // Phase B: layer2 matvec: Wih2(reg bf16)*h1[t-2] + Whh2(LDS bf16)*h2[t-3]
      const f32x4* h1B = h1buf[t & 1];
      #pragma unroll
      for (int rr = 0; rr < 4; ++rr) {
        const int lr = wv * 4 + rr;
        float s = 0.f;
        #pragma unroll
        for (int q = 0; q < 2; ++q) {
          const int u = lane + 64 * q;
          u32x4 w = wi_reg[rr][q];
          f32x4 ha = h1B[u];
          f32x4 hb = h1B[128 + u];
          s += bf_lo(w[0]) * ha[0] + bf_hi(w[0]) * ha[1]
             + bf_lo(w[1]) * ha[2] + bf_hi(w[1]) * ha[3];
          s += bf_lo(w[2]) * hb[0] + bf_hi(w[2]) * hb[1]
             + bf_lo(w[3]) * hb[2] + bf_hi(w[3]) * hb[3];
        }
        #pragma unroll
        for (int q = 0; q < 4; ++q) {
          const int u = lane + 64 * q;
          u32x4 w = whh2_u4[lr * 256 + u];
          f32x4 ha = h2_4[u];
          f32x4 hb = h2_4[256 + u];
          s += bf_lo(w[0]) * ha[0] + bf_hi(w[0]) * ha[1]
             + bf_lo(w[1]) * ha[2] + bf_hi(w[1]) * ha[3];
          s += bf_lo(w[2]) * hb[0] + bf_hi(w[2]) * hb[1]
             + bf_lo(w[3]) * hb[2] + bf_hi(w[3]) * hb[3];
        }
        s = wave_reduce(s);
        if (lane == 0) gsum2[lr] = s;
      }
    }
    __syncthreads();   // gsums ready; all LDS h reads of this iter done

    if (wv == 0) {
      float h1v = 0.f, h2v = 0.f;
      if (t < T_STEPS) {
        const int u1 = lane & 3;
        float gi = sigmoidf_(gsum1[u1]      + gx1v[u1]);
        float gf = sigmoidf_(gsum1[4 + u1]  + gx1v[4 + u1]);
        float gg = tanhf    (gsum1[8 + u1]  + gx1v[8 + u1]);
        float go = sigmoidf_(gsum1[12 + u1] + gx1v[12 + u1]);
        c1reg = gf * c1reg + gi * gg;
        h1v = go * tanhf(c1reg);               // unit (lane&3)
      }
      if (t >= 2) {
        const int u2 = lane & 7;
        float gi = sigmoidf_(gsum2[u2]      + b2v[u2]);
        float gf = sigmoidf_(gsum2[8 + u2]  + b2v[8 + u2]);
        float gg = tanhf    (gsum2[16 + u2] + b2v[16 + u2]);
        float go = sigmoidf_(gsum2[24 + u2] + b2v[24 + u2]);
        c2reg = gf * c2reg + gi * gg;
        h2v = go * tanhf(c2reg);               // unit (lane&7)
      }
      // ---- publish FIRST (critical path), 16 copies via 4 wave-stores ----
      const int p = lane & 15;                 // pair index
      float a1  = __shfl(h1v, p & 3);
      float a2  = __shfl(h2v, (p - 4) & 7);
      float pay = (p < 4) ? a1 : ((p < 12) ? a2 : 0.f);
      u32x2 st;
      st[0] = __float_as_uint(pay);
      st[1] = (uint32_t)(t + 1);
      uint32_t* base = combined
        + ((((size_t)(t & 3) * NCU + b) * NCOPY + (lane >> 4)) * LINE_DW) + 2 * p;
      #pragma unroll
      for (int k = 0; k < 4; ++k) {
        uint32_t* pp = base + (size_t)k * 4 * LINE_DW;   // copies (lane>>4)+4k
        asm volatile("global_store_dwordx2 %0, %1, off sc0 sc1"
                     :: "v"(pp), "v"(st) : "memory");
      }
      // ---- then the output projection partial ----
      if (t >= 2) {
        float contrib = (lane < 8) ? h2v * woutreg : 0.f;
        float po = wave_reduce(contrib);
        if (lane == 0) partial_out[(int64_t)(t - 2) * NCU + b] = po;
      }
    }

    // waves 4..7: poll+gather one source line each from our copy
    if (tid >= NCU) {
      const int j = tid - NCU;                 // source block
      const uint32_t* line = combined
        + ((((size_t)(t & 3) * NCU + j) * NCOPY + (b >> 4)) * LINE_DW);
      const uint32_t tg = (uint32_t)(t + 1);
      // stage 1: cheap probe on pair 11's tag (last stored pair)
      u32x2 q;
      for (;;) {
        asm volatile("global_load_dwordx2 %0, %1, off offset:88 sc0 sc1"
                     : "=&v"(q) : "v"(line));
        asm volatile("s_waitcnt vmcnt(0)" ::: "memory");
        if (q[1] == tg) break;
        __builtin_amdgcn_s_sleep(1);
      }
      // stage 2: full load, verify every tag
      u32x4 p0, p1, p2, p3, p4, p5;
      for (;;) {
        asm volatile("global_load_dwordx4 %0, %1, off sc0 sc1"
                     : "=&v"(p0) : "v"(line));
        asm volatile("global_load_dwordx4 %0, %1, off offset:16 sc0 sc1"
                     : "=&v"(p1) : "v"(line));
        asm volatile("global_load_dwordx4 %0, %1, off offset:32 sc0 sc1"
                     : "=&v"(p2) : "v"(line));
        asm volatile("global_load_dwordx4 %0, %1, off offset:48 sc0 sc1"
                     : "=&v"(p3) : "v"(line));
        asm volatile("global_load_dwordx4 %0, %1, off offset:64 sc0 sc1"
                     : "=&v"(p4) : "v"(line));
        asm volatile("global_load_dwordx4 %0, %1, off offset:80 sc0 sc1"
                     : "=&v"(p5) : "v"(line));
        asm volatile("s_waitcnt vmcnt(0)" ::: "memory");
        bool ok = (p0[1]==tg) & (p0[3]==tg) & (p1[1]==tg) & (p1[3]==tg)
                & (p2[1]==tg) & (p2[3]==tg) & (p3[1]==tg) & (p3[3]==tg)
                & (p4[1]==tg) & (p4[3]==tg) & (p5[1]==tg) & (p5[3]==tg);
        if (ok) break;
        __builtin_amdgcn_s_sleep(1);
      }
      f32x4 h1w;
      h1w[0] = __uint_as_float(p0[0]); h1w[1] = __uint_as_float(p0[2]);
      h1w[2] = __uint_as_float(p1[0]); h1w[3] = __uint_as_float(p1[2]);
      h1buf[t & 1][j] = h1w;             // becomes h1[t]
      f32x4 h2a, h2b;
      h2a[0] = __uint_as_float(p2[0]); h2a[1] = __uint_as_float(p2[2]);
      h2a[2] = __uint_as_float(p3[0]); h2a[3] = __uint_as_float(p3[2]);
      h2b[0] = __uint_as_float(p4[0]); h2b[1] = __uint_as_float(p4[2]);
      h2b[2] = __uint_as_float(p5[0]); h2b[3] = __uint_as_float(p5[2]);
      h2_4[2 * j]     = h2a;             // becomes h2[t-2]
      h2_4[2 * j + 1] = h2b;
    }
    __syncthreads();
  }
}

// ---------------------------------------------------------------------------
// out[t] = sum_b partial_out[t][b] + bout
// ---------------------------------------------------------------------------
__global__ void out_reduce(const float* __restrict__ partial_out,
                           const float* __restrict__ bout,
                           float* __restrict__ out)
{
  int t = blockIdx.x;
  int lane = threadIdx.x;   // 64 threads
  float s = 0.f;
  #pragma unroll
  for (int q = 0; q < 4; ++q) s += partial_out[(int64_t)t * NCU + lane + 64 * q];
  s = wave_reduce(s);
  if (lane == 0) out[t] = s + bout[0];
}

extern "C" void kernel_launch(void* const* d_in, const int* in_sizes, int n_in,
                              void* d_out, int out_size, void* d_ws, size_t ws_size,
                              hipStream_t stream)
{
  const float* x    = (const float*)d_in[0];
  const float* Wih1 = (const float*)d_in[1];
  const float* Whh1 = (const float*)d_in[2];
  const float* b1   = (const float*)d_in[3];
  const float* Wih2 = (const float*)d_in[4];
  const float* Whh2 = (const float*)d_in[5];
  const float* b2   = (const float*)d_in[6];
  const float* Wout = (const float*)d_in[7];
  const float* bout = (const float*)d_in[8];
  float* out = (float*)d_out;

  char* ws = (char*)d_ws;
  size_t off = 0;
  auto take = [&](size_t bytes) -> char* {
    char* p = ws + off;
    off = (off + bytes + 255) & ~(size_t)255;
    return p;
  };
  uint32_t* combined  = (uint32_t*)take((size_t)4 * NCU * NCOPY * LINE_DW * 4); // 2 MB
  float* partial_out  = (float*)take((size_t)T_STEPS * NCU * 4);                // 2 MB

  if (off > ws_size) return;

  hipLaunchKernelGGL(prep_kernel, dim3(256), dim3(256), 0, stream, combined);

  void* args[] = { &x, &Wih1, &Whh1, &b1, &Wih2, &Whh2, &b2, &Wout,
                   &combined, &partial_out };
  (void)hipLaunchCooperativeKernel((void*)lstm_persist, dim3(NCU), dim3(TPB),
                                   args, 0, stream);

  hipLaunchKernelGGL(out_reduce, dim3(T_STEPS), dim3(64), 0, stream,
                     partial_out, bout, out);
}

// Round 7
// 13582.286 us; speedup vs baseline: 1.2671x; 1.2671x over previous
//
#include <hip/hip_runtime.h>
#include <stdint.h>

#define NCU 256
#define TPB 512
#define IN_DIM 1024
#define HID1   1024
#define HID2   2048
#define T_STEPS 2048

// 64-B exchange line: dw0..3 h1, dw4..11 h2, dw12 flag, dw13..15 pad.
// Flag is IN THE SAME 64-B line as the data: same-line stores reach the L3
// bank in order, so flag-visible => data-visible (validated in round 3).
#define LINE_DW 16

typedef float    f32x4 __attribute__((ext_vector_type(4)));
typedef uint32_t u32x4 __attribute__((ext_vector_type(4)));

__device__ __forceinline__ float bf_lo(uint32_t u){ return __uint_as_float(u << 16); }
__device__ __forceinline__ float bf_hi(uint32_t u){ return __uint_as_float(u & 0xffff0000u); }
__device__ __forceinline__ uint32_t f2bf(float f){
  uint32_t x = __float_as_uint(f);
  return (x + 0x7fffu + ((x >> 16) & 1u)) >> 16;   // RNE
}
__device__ __forceinline__ uint32_t pack2(float a, float b){
  return f2bf(a) | (f2bf(b) << 16);
}
__device__ __forceinline__ float wave_reduce(float v){
  v += __shfl_xor(v, 32); v += __shfl_xor(v, 16); v += __shfl_xor(v, 8);
  v += __shfl_xor(v, 4);  v += __shfl_xor(v, 2);  v += __shfl_xor(v, 1);
  return v;
}
__device__ __forceinline__ float sigmoidf_(float x){ return 1.0f / (1.0f + expf(-x)); }

__global__ void prep_kernel(uint32_t* __restrict__ lines)
{
  int idx = blockIdx.x * blockDim.x + threadIdx.x;
  const int total = 4 * NCU * LINE_DW;
  for (int i = idx; i < total; i += gridDim.x * blockDim.x)
    __hip_atomic_store(lines + i, 0u, __ATOMIC_RELAXED, __HIP_MEMORY_SCOPE_AGENT);
}

// ---------------------------------------------------------------------------
// persistent 2-layer LSTM scan. 256 blocks (1/CU) x 512 threads.
// Block b owns layer1 units [4b,4b+4) and layer2 units [8b,8b+8).
// Iteration t computes h1[t] (phase A, needs h1[t-1]) and h2[t-2]
// (phase B, needs h1[t-2], h2[t-3]). ONE exchange per iteration:
//   wave 0:    gates -> publish 64-B line (48B data, vmcnt(0), flag dw12)
//   waves 4-7: thread j polls line j's flag, gathers 48B when ready
// Two __syncthreads per iteration.
// ---------------------------------------------------------------------------
__global__ __launch_bounds__(TPB, 1) void lstm_persist(
    const float* __restrict__ x,    const float* __restrict__ Wih1,
    const float* __restrict__ Whh1, const float* __restrict__ b1,
    const float* __restrict__ Wih2, const float* __restrict__ Whh2,
    const float* __restrict__ b2,   const float* __restrict__ Wout,
    uint32_t* __restrict__ lines,   float* __restrict__ partial_out)
{
  __shared__ u32x4 whh2_u4[32 * 256];    // 128 KiB bf16 Whh2 slice
  __shared__ f32x4 h1buf[2][HID1 / 4];   // double-buffered h1 (2 x 4 KiB)
  __shared__ f32x4 h2_4[HID2 / 4];       // h2[t-3] (8 KiB)
  __shared__ float gsum1[16], gx1v[16], gsum2[32], b2v[32];

  const int b    = blockIdx.x;
  const int tid  = threadIdx.x;
  const int lane = tid & 63;
  const int wv   = tid >> 6;   // 8 waves

  // ---- init: stage Whh2 slice into LDS (fp32 -> bf16, paired-block layout) --
  for (int i = tid; i < 32 * 256; i += TPB) {
    int lr = i >> 8, u = i & 255;
    int g = lr >> 3, uu2 = lr & 7;
    const f32x4* s4 = (const f32x4*)(Whh2 + (int64_t)(g * HID2 + 8 * b + uu2) * HID2);
    f32x4 lo = s4[u], hi = s4[256 + u];
    u32x4 wv4;
    wv4[0] = pack2(lo[0], lo[1]); wv4[1] = pack2(lo[2], lo[3]);
    wv4[2] = pack2(hi[0], hi[1]); wv4[3] = pack2(hi[2], hi[3]);
    whh2_u4[i] = wv4;
  }

  // ---- Whh1 slice in registers (fp32, 2 rows/wave, 16 elems/lane/row) ----
  float w1r[2][16];
  int rows1[2];
  #pragma unroll
  for (int rr = 0; rr < 2; ++rr) {
    int lr1 = wv * 2 + rr;
    int g = lr1 >> 2, uu = lr1 & 3;
    int row = g * HID1 + 4 * b + uu;
    rows1[rr] = row;
    #pragma unroll
    for (int j = 0; j < 16; ++j)
      w1r[rr][j] = Whh1[(int64_t)row * IN_DIM + lane + 64 * j];
  }

  // ---- Wih2 slice in registers (bf16 packed, paired-block layout) ----
  u32x4 wi_reg[4][2];
  #pragma unroll
  for (int rr = 0; rr < 4; ++rr) {
    int lr = wv * 4 + rr;
    int g = lr >> 3, uu = lr & 7;
    const f32x4* s4 = (const f32x4*)(Wih2 + (int64_t)(g * HID2 + 8 * b + uu) * IN_DIM);
    #pragma unroll
    for (int q = 0; q < 2; ++q) {
      int u = lane + 64 * q;
      f32x4 lo = s4[u], hi = s4[128 + u];
      u32x4 wv4;
      wv4[0] = pack2(lo[0], lo[1]); wv4[1] = pack2(lo[2], lo[3]);
      wv4[2] = pack2(hi[0], hi[1]); wv4[3] = pack2(hi[2], hi[3]);
      wi_reg[rr][q] = wv4;
    }
  }

  // ---- gx1 = Wih1 @ x + b1 (constant over t) ----
  #pragma unroll
  for (int rr = 0; rr < 2; ++rr) {
    int row = rows1[rr];
    float s = 0.f;
    #pragma unroll
    for (int j = 0; j < 16; ++j)
      s += Wih1[(int64_t)row * IN_DIM + lane + 64 * j] * x[lane + 64 * j];
    s = wave_reduce(s);
    if (lane == 0) gx1v[wv * 2 + rr] = s + b1[row];
  }
  if (tid < 32) { int g = tid >> 3, uu = tid & 7; b2v[tid] = b2[g * HID2 + 8 * b + uu]; }
  {
    float* h1a  = (float*)h1buf[0];
    float* h1bb = (float*)h1buf[1];
    float* h2a  = (float*)h2_4;
    for (int i = tid; i < HID1; i += TPB) { h1a[i] = 0.f; h1bb[i] = 0.f; }
    for (int i = tid; i < HID2; i += TPB) h2a[i] = 0.f;
  }

  const float woutreg = Wout[8 * b + (lane & 7)];
  float c1reg = 0.f, c2reg = 0.f;
  __syncthreads();

  // ---- time loop ----
  for (int t = 0; t < T_STEPS + 2; ++t) {
    if (t < T_STEPS) {
      // Phase A: layer1 recurrent matvec over h1[t-1]
      const float* h1A = (const float*)h1buf[(t + 1) & 1];
      #pragma unroll
      for (int rr = 0; rr < 2; ++rr) {
        float s = 0.f;
        #pragma unroll
        for (int j = 0; j < 16; ++j) s += w1r[rr][j] * h1A[lane + 64 * j];
        s = wave_reduce(s);
        if (lane == 0) gsum1[wv * 2 + rr] = s;
      }
    }
    if (t >= 2) {
      // Phase B: layer2 matvec: Wih2(reg bf16)*h1[t-2] + Whh2(LDS bf16)*h2[t-3]
      const f32x4* h1B = h1buf[t & 1];
      #pragma unroll
      for (int rr = 0; rr < 4; ++rr) {
        const int lr = wv * 4 + rr;
        float s = 0.f;
        #pragma unroll
        for (int q = 0; q < 2; ++q) {
          const int u = lane + 64 * q;
          u32x4 w = wi_reg[rr][q];
          f32x4 ha = h1B[u];
          f32x4 hb = h1B[128 + u];
          s += bf_lo(w[0]) * ha[0] + bf_hi(w[0]) * ha[1]
             + bf_lo(w[1]) * ha[2] + bf_hi(w[1]) * ha[3];
          s += bf_lo(w[2]) * hb[0] + bf_hi(w[2]) * hb[1]
             + bf_lo(w[3]) * hb[2] + bf_hi(w[3]) * hb[3];
        }
        #pragma unroll
        for (int q = 0; q < 4; ++q) {
          const int u = lane + 64 * q;
          u32x4 w = whh2_u4[lr * 256 + u];
          f32x4 ha = h2_4[u];
          f32x4 hb = h2_4[256 + u];
          s += bf_lo(w[0]) * ha[0] + bf_hi(w[0]) * ha[1]
             + bf_lo(w[1]) * ha[2] + bf_hi(w[1]) * ha[3];
          s += bf_lo(w[2]) * hb[0] + bf_hi(w[2]) * hb[1]
             + bf_lo(w[3]) * hb[2] + bf_hi(w[3]) * hb[3];
        }
        s = wave_reduce(s);
        if (lane == 0) gsum2[lr] = s;
      }
    }
    __syncthreads();   // sync1: gsums ready; LDS h reads of this iter done

    if (wv == 0) {
      float h1v = 0.f, h2v = 0.f;
      if (t < T_STEPS) {
        const int u1 = lane & 3;
        float gi = sigmoidf_(gsum1[u1]      + gx1v[u1]);
        float gf = sigmoidf_(gsum1[4 + u1]  + gx1v[4 + u1]);
        float gg = tanhf    (gsum1[8 + u1]  + gx1v[8 + u1]);
        float go = sigmoidf_(gsum1[12 + u1] + gx1v[12 + u1]);
        c1reg = gf * c1reg + gi * gg;
        h1v = go * tanhf(c1reg);               // unit (lane&3)
      }
      if (t >= 2) {
        const int u2 = lane & 7;
        float gi = sigmoidf_(gsum2[u2]      + b2v[u2]);
        float gf = sigmoidf_(gsum2[8 + u2]  + b2v[8 + u2]);
        float gg = tanhf    (gsum2[16 + u2] + b2v[16 + u2]);
        float go = sigmoidf_(gsum2[24 + u2] + b2v[24 + u2]);
        c2reg = gf * c2reg + gi * gg;
        h2v = go * tanhf(c2reg);               // unit (lane&7)
      }
      if (t <= T_STEPS) {
        // ---- publish: lanes 0-2 store 16B data, ack, flag in SAME line ----
        uint32_t* lineW = lines + ((size_t)(t & 3) * NCU + b) * LINE_DW;
        f32x4 st;
        const int base = (lane == 2) ? 4 : 0;
        #pragma unroll
        for (int c2 = 0; c2 < 4; ++c2) {
          float a  = __shfl(h1v, c2);
          float bb = __shfl(h2v, base + c2);
          st[c2] = (lane == 0) ? a : bb;
        }
        float* p = (float*)(lineW + 4 * lane);
        if (lane < 3)
          asm volatile("global_store_dwordx4 %0, %1, off sc0 sc1"
                       :: "v"(p), "v"(st) : "memory");
        asm volatile("s_waitcnt vmcnt(0)" ::: "memory");
        if (lane == 0)
          __hip_atomic_store((int*)(lineW + 12), t + 1,
                             __ATOMIC_RELAXED, __HIP_MEMORY_SCOPE_AGENT);
      }
      // ---- off the critical path: output projection partial ----
      if (t >= 2) {
        float contrib = (lane < 8) ? h2v * woutreg : 0.f;
        float po = wave_reduce(contrib);
        if (lane == 0) partial_out[(int64_t)(t - 2) * NCU + b] = po;
      }
    }

    // ---- waves 4-7: thread j polls line j's flag, then gathers 48B ----
    if (t <= T_STEPS && tid >= NCU) {
      const int j = tid - NCU;
      const uint32_t* line = lines + ((size_t)(t & 3) * NCU + j) * LINE_DW;
      const int tg = t + 1;
      while (__hip_atomic_load((const int*)(line + 12),
                               __ATOMIC_RELAXED, __HIP_MEMORY_SCOPE_AGENT) < tg)
        __builtin_amdgcn_s_sleep(1);
      f32x4 a, bb, cc;
      asm volatile("global_load_dwordx4 %0, %1, off sc0 sc1"
                   : "=&v"(a)  : "v"(line));
      asm volatile("global_load_dwordx4 %0, %1, off offset:16 sc0 sc1"
                   : "=&v"(bb) : "v"(line));
      asm volatile("global_load_dwordx4 %0, %1, off offset:32 sc0 sc1"
                   : "=&v"(cc) : "v"(line));
      asm volatile("s_waitcnt vmcnt(0)" ::: "memory");
      h1buf[t & 1][j] = a;               // becomes h1[t]
      h2_4[2 * j]     = bb;              // becomes h2[t-2]
      h2_4[2 * j + 1] = cc;
    }
    __syncthreads();   // sync2
  }
}

// ---------------------------------------------------------------------------
// out[t] = sum_b partial_out[t][b] + bout
// ---------------------------------------------------------------------------
__global__ void out_reduce(const float* __restrict__ partial_out,
                           const float* __restrict__ bout,
                           float* __restrict__ out)
{
  int t = blockIdx.x;
  int lane = threadIdx.x;   // 64 threads
  float s = 0.f;
  #pragma unroll
  for (int q = 0; q < 4; ++q) s += partial_out[(int64_t)t * NCU + lane + 64 * q];
  s = wave_reduce(s);
  if (lane == 0) out[t] = s + bout[0];
}

extern "C" void kernel_launch(void* const* d_in, const int* in_sizes, int n_in,
                              void* d_out, int out_size, void* d_ws, size_t ws_size,
                              hipStream_t stream)
{
  const float* x    = (const float*)d_in[0];
  const float* Wih1 = (const float*)d_in[1];
  const float* Whh1 = (const float*)d_in[2];
  const float* b1   = (const float*)d_in[3];
  const float* Wih2 = (const float*)d_in[4];
  const float* Whh2 = (const float*)d_in[5];
  const float* b2   = (const float*)d_in[6];
  const float* Wout = (const float*)d_in[7];
  const float* bout = (const float*)d_in[8];
  float* out = (float*)d_out;

  char* ws = (char*)d_ws;
  size_t off = 0;
  auto take = [&](size_t bytes) -> char* {
    char* p = ws + off;
    off = (off + bytes + 255) & ~(size_t)255;
    return p;
  };
  uint32_t* lines    = (uint32_t*)take((size_t)4 * NCU * LINE_DW * 4);  // 64 KB
  float* partial_out = (float*)take((size_t)T_STEPS * NCU * 4);         // 2 MB

  if (off > ws_size) return;

  hipLaunchKernelGGL(prep_kernel, dim3(16), dim3(256), 0, stream, lines);

  void* args[] = { &x, &Wih1, &Whh1, &b1, &Wih2, &Whh2, &b2, &Wout,
                   &lines, &partial_out };
  (void)hipLaunchCooperativeKernel((void*)lstm_persist, dim3(NCU), dim3(TPB),
                                   args, 0, stream);

  hipLaunchKernelGGL(out_reduce, dim3(T_STEPS), dim3(64), 0, stream,
                     partial_out, bout, out);
}

// Round 9
// 10872.163 us; speedup vs baseline: 1.5829x; 1.2493x over previous
//
#include <hip/hip_runtime.h>
#include <stdint.h>

#define NCU 256
#define TPB 512
#define IN_DIM 1024
#define HID1   1024
#define HID2   2048
#define T_STEPS 2048

// 64-B exchange line: dw0..3 h1, dw4..11 h2, dw12 flag, dw13..15 pad.
// Flag IN THE SAME 64-B line as data: same-line stores cannot reorder
// (proven r3/r7; cross-line flag after vmcnt(0) raced in r6 - never again).
#define LINE_DW 16

typedef float    f32x4 __attribute__((ext_vector_type(4)));
typedef uint32_t u32x4 __attribute__((ext_vector_type(4)));
typedef uint32_t u32x2 __attribute__((ext_vector_type(2)));
typedef __fp16   h16x2 __attribute__((ext_vector_type(2)));

// pack 2 f32 -> 2 f16 (RTZ) in one dword
__device__ __forceinline__ uint32_t pkh(float a, float b){
  h16x2 h = __builtin_amdgcn_cvt_pkrtz(a, b);
  uint32_t u; __builtin_memcpy(&u, &h, 4); return u;
}

#if __has_builtin(__builtin_amdgcn_fdot2)
__device__ __forceinline__ float fdot2_(uint32_t w, uint32_t h, float c){
  h16x2 wf, hf; __builtin_memcpy(&wf, &w, 4); __builtin_memcpy(&hf, &h, 4);
  return __builtin_amdgcn_fdot2(wf, hf, c, false);
}
#else
__device__ __forceinline__ float fdot2_(uint32_t w, uint32_t h, float c){
  h16x2 wf, hf; __builtin_memcpy(&wf, &w, 4); __builtin_memcpy(&hf, &h, 4);
  c = fmaf((float)wf[0], (float)hf[0], c);
  return fmaf((float)wf[1], (float)hf[1], c);
}
#endif

__device__ __forceinline__ float dot16(u32x4 w, u32x4 h, float c){
  c = fdot2_(w[0], h[0], c); c = fdot2_(w[1], h[1], c);
  c = fdot2_(w[2], h[2], c); c = fdot2_(w[3], h[3], c);
  return c;
}

__device__ __forceinline__ float wave_reduce(float v){
  v += __shfl_xor(v, 32); v += __shfl_xor(v, 16); v += __shfl_xor(v, 8);
  v += __shfl_xor(v, 4);  v += __shfl_xor(v, 2);  v += __shfl_xor(v, 1);
  return v;
}

// fast gates: v_exp-based sigmoid/tanh + v_rcp (error ~1e-7, << f16 quant)
__device__ __forceinline__ float sigm_(float x){
  return __builtin_amdgcn_rcpf(1.f + __expf(-x));
}
__device__ __forceinline__ float tanh_(float x){
  float e = __expf(2.f * x);
  return (e - 1.f) * __builtin_amdgcn_rcpf(e + 1.f);
}

__global__ void prep_kernel(uint32_t* __restrict__ lines)
{
  int idx = blockIdx.x * blockDim.x + threadIdx.x;
  const int total = 4 * NCU * LINE_DW;
  for (int i = idx; i < total; i += gridDim.x * blockDim.x)
    __hip_atomic_store(lines + i, 0u, __ATOMIC_RELAXED, __HIP_MEMORY_SCOPE_AGENT);
}

// ---------------------------------------------------------------------------
// persistent 2-layer LSTM scan. 256 blocks (1/CU) x 512 threads.
// Block b owns layer1 units [4b,4b+4) and layer2 units [8b,8b+8).
// Iteration t computes h1[t] (phase A, needs h1[t-1]) and h2[t-2]
// (phase B, needs h1[t-2], h2[t-3]). ONE exchange per iteration (r7 protocol).
// All matvecs in packed-f16 dot2; h stored in LDS as packed f16 "granules":
// granule u (u32x4 = 4 pair-dwords) covers h elements 8u..8u+7.
// ---------------------------------------------------------------------------
__global__ __launch_bounds__(TPB, 1) void lstm_persist(
    const float* __restrict__ x,    const float* __restrict__ Wih1,
    const float* __restrict__ Whh1, const float* __restrict__ b1,
    const float* __restrict__ Wih2, const float* __restrict__ Whh2,
    const float* __restrict__ b2,   const float* __restrict__ Wout,
    uint32_t* __restrict__ lines,   float* __restrict__ partial_out)
{
  __shared__ u32x4 whh2_u4[32 * 256];   // 128 KiB f16 Whh2 slice (granules)
  __shared__ u32x4 h1g[2][128];         // h1 packed f16, double-buffered (2x2KB)
  __shared__ u32x4 h2g[256];            // h2[t-3] packed f16 (4KB)
  __shared__ float gsum1[16], gx1v[16], gsum2[32], b2v[32];

  const int b    = blockIdx.x;
  const int tid  = threadIdx.x;
  const int lane = tid & 63;
  const int wv   = tid >> 6;   // 8 waves

  // ---- init: stage Whh2 slice into LDS (fp32 -> f16 granules) ----
  for (int i = tid; i < 32 * 256; i += TPB) {
    int lr = i >> 8, u = i & 255;
    int g = lr >> 3, uu2 = lr & 7;
    const f32x4* s4 = (const f32x4*)(Whh2 + (int64_t)(g * HID2 + 8 * b + uu2) * HID2);
    f32x4 lo = s4[2 * u], hi = s4[2 * u + 1];
    u32x4 wv4;
    wv4[0] = pkh(lo[0], lo[1]); wv4[1] = pkh(lo[2], lo[3]);
    wv4[2] = pkh(hi[0], hi[1]); wv4[3] = pkh(hi[2], hi[3]);
    whh2_u4[i] = wv4;
  }

  // ---- Whh1 slice in registers (f16 granules, 2 rows/wave) ----
  u32x4 w1g[2][2];
  int rows1[2];
  #pragma unroll
  for (int rr = 0; rr < 2; ++rr) {
    int lr1 = wv * 2 + rr;
    int g = lr1 >> 2, uu = lr1 & 3;
    int row = g * HID1 + 4 * b + uu;
    rows1[rr] = row;
    const f32x4* s4 = (const f32x4*)(Whh1 + (int64_t)row * IN_DIM);
    #pragma unroll
    for (int q = 0; q < 2; ++q) {
      int u = lane + 64 * q;
      f32x4 lo = s4[2 * u], hi = s4[2 * u + 1];
      u32x4 wv4;
      wv4[0] = pkh(lo[0], lo[1]); wv4[1] = pkh(lo[2], lo[3]);
      wv4[2] = pkh(hi[0], hi[1]); wv4[3] = pkh(hi[2], hi[3]);
      w1g[rr][q] = wv4;
    }
  }

  // ---- Wih2 slice in registers (f16 granules, 4 rows/wave) ----
  u32x4 wi_reg[4][2];
  #pragma unroll
  for (int rr = 0; rr < 4; ++rr) {
    int lr = wv * 4 + rr;
    int g = lr >> 3, uu = lr & 7;
    const f32x4* s4 = (const f32x4*)(Wih2 + (int64_t)(g * HID2 + 8 * b + uu) * IN_DIM);
    #pragma unroll
    for (int q = 0; q < 2; ++q) {
      int u = lane + 64 * q;
      f32x4 lo = s4[2 * u], hi = s4[2 * u + 1];
      u32x4 wv4;
      wv4[0] = pkh(lo[0], lo[1]); wv4[1] = pkh(lo[2], lo[3]);
      wv4[2] = pkh(hi[0], hi[1]); wv4[3] = pkh(hi[2], hi[3]);
      wi_reg[rr][q] = wv4;
    }
  }

  // ---- gx1 = Wih1 @ x + b1 (constant over t; fp32, init-only) ----
  #pragma unroll
  for (int rr = 0; rr < 2; ++rr) {
    int row = rows1[rr];
    float s = 0.f;
    #pragma unroll
    for (int j = 0; j < 16; ++j)
      s += Wih1[(int64_t)row * IN_DIM + lane + 64 * j] * x[lane + 64 * j];
    s = wave_reduce(s);
    if (lane == 0) gx1v[wv * 2 + rr] = s + b1[row];
  }
  if (tid < 32) { int g = tid >> 3, uu = tid & 7; b2v[tid] = b2[g * HID2 + 8 * b + uu]; }
  {
    uint32_t* p1 = (uint32_t*)h1g;
    uint32_t* p2 = (uint32_t*)h2g;
    for (int i = tid; i < 2 * 128 * 4; i += TPB) p1[i] = 0u;
    for (int i = tid; i < 256 * 4;     i += TPB) p2[i] = 0u;
  }

  const float woutreg = Wout[8 * b + (lane & 7)];
  float c1reg = 0.f, c2reg = 0.f;
  __syncthreads();

  // ---- time loop ----
  for (int t = 0; t < T_STEPS + 2; ++t) {
    if (t < T_STEPS) {
      // Phase A: layer1 recurrent matvec over h1[t-1] (f16 dot2)
      const u32x4* h1A = h1g[(t + 1) & 1];
      u32x4 ha0 = h1A[lane], ha1 = h1A[64 + lane];
      #pragma unroll
      for (int rr = 0; rr < 2; ++rr) {
        float s = dot16(w1g[rr][0], ha0, 0.f);
        s = dot16(w1g[rr][1], ha1, s);
        s = wave_reduce(s);
        if (lane == 0) gsum1[wv * 2 + rr] = s;
      }
    }
    if (t >= 2) {
      // Phase B: layer2 matvec: Wih2(reg)*h1[t-2] + Whh2(LDS)*h2[t-3]
      const u32x4* h1B = h1g[t & 1];
      u32x4 x1a = h1B[lane], x1b = h1B[64 + lane];
      u32x4 x20 = h2g[lane],       x21 = h2g[64 + lane];
      u32x4 x22 = h2g[128 + lane], x23 = h2g[192 + lane];
      #pragma unroll
      for (int rr = 0; rr < 4; ++rr) {
        const int lr = wv * 4 + rr;
        float s = dot16(wi_reg[rr][0], x1a, 0.f);
        s = dot16(wi_reg[rr][1], x1b, s);
        s = dot16(whh2_u4[lr * 256 + lane],       x20, s);
        s = dot16(whh2_u4[lr * 256 + 64 + lane],  x21, s);
        s = dot16(whh2_u4[lr * 256 + 128 + lane], x22, s);
        s = dot16(whh2_u4[lr * 256 + 192 + lane], x23, s);
        s = wave_reduce(s);
        if (lane == 0) gsum2[lr] = s;
      }
    }
    __syncthreads();   // sync1: gsums ready; LDS h reads of this iter done

    if (wv == 0) {
      float h1v = 0.f, h2v = 0.f;
      if (t < T_STEPS) {
        const int u1 = lane & 3;
        float gi = sigm_(gsum1[u1]      + gx1v[u1]);
        float gf = sigm_(gsum1[4 + u1]  + gx1v[4 + u1]);
        float gg = tanh_(gsum1[8 + u1]  + gx1v[8 + u1]);
        float go = sigm_(gsum1[12 + u1] + gx1v[12 + u1]);
        c1reg = gf * c1reg + gi * gg;
        h1v = go * tanh_(c1reg);               // unit (lane&3)
      }
      if (t >= 2) {
        const int u2 = lane & 7;
        float gi = sigm_(gsum2[u2]      + b2v[u2]);
        float gf = sigm_(gsum2[8 + u2]  + b2v[8 + u2]);
        float gg = tanh_(gsum2[16 + u2] + b2v[16 + u2]);
        float go = sigm_(gsum2[24 + u2] + b2v[24 + u2]);
        c2reg = gf * c2reg + gi * gg;
        h2v = go * tanh_(c2reg);               // unit (lane&7)
      }
      if (t <= T_STEPS) {
        // ---- publish: lanes 0-2 store 16B data, ack, flag in SAME line ----
        uint32_t* lineW = lines + ((size_t)(t & 3) * NCU + b) * LINE_DW;
        f32x4 st;
        const int base = (lane == 2) ? 4 : 0;
        #pragma unroll
        for (int c2 = 0; c2 < 4; ++c2) {
          float a  = __shfl(h1v, c2);
          float bb = __shfl(h2v, base + c2);
          st[c2] = (lane == 0) ? a : bb;
        }
        float* p = (float*)(lineW + 4 * lane);
        if (lane < 3)
          asm volatile("global_store_dwordx4 %0, %1, off sc0 sc1"
                       :: "v"(p), "v"(st) : "memory");
        asm volatile("s_waitcnt vmcnt(0)" ::: "memory");
        if (lane == 0)
          __hip_atomic_store((int*)(lineW + 12), t + 1,
                             __ATOMIC_RELAXED, __HIP_MEMORY_SCOPE_AGENT);
      }
      // ---- off the critical path: output projection partial ----
      if (t >= 2) {
        float contrib = (lane < 8) ? h2v * woutreg : 0.f;
        float po = wave_reduce(contrib);
        if (lane == 0) partial_out[(int64_t)(t - 2) * NCU + b] = po;
      }
    }

    // ---- waves 4-7: thread j polls line j's flag, gathers, packs to f16 ----
    if (t <= T_STEPS && tid >= NCU) {
      const int j = tid - NCU;
      const uint32_t* line = lines + ((size_t)(t & 3) * NCU + j) * LINE_DW;
      const int tg = t + 1;
      while (__hip_atomic_load((const int*)(line + 12),
                               __ATOMIC_RELAXED, __HIP_MEMORY_SCOPE_AGENT) < tg)
        __builtin_amdgcn_s_sleep(1);
      f32x4 a, bb, cc;
      asm volatile("global_load_dwordx4 %0, %1, off sc0 sc1"
                   : "=&v"(a)  : "v"(line));
      asm volatile("global_load_dwordx4 %0, %1, off offset:16 sc0 sc1"
                   : "=&v"(bb) : "v"(line));
      asm volatile("global_load_dwordx4 %0, %1, off offset:32 sc0 sc1"
                   : "=&v"(cc) : "v"(line));
      asm volatile("s_waitcnt vmcnt(0)" ::: "memory");
      u32x2 h1p; h1p[0] = pkh(a[0], a[1]); h1p[1] = pkh(a[2], a[3]);
      ((u32x2*)h1g[t & 1])[j] = h1p;       // becomes h1[t] (units 4j..4j+3)
      u32x4 h2p;
      h2p[0] = pkh(bb[0], bb[1]); h2p[1] = pkh(bb[2], bb[3]);
      h2p[2] = pkh(cc[0], cc[1]); h2p[3] = pkh(cc[2], cc[3]);
      h2g[j] = h2p;                        // becomes h2[t-2] (units 8j..8j+7)
    }
    __syncthreads();   // sync2
  }
}

// ---------------------------------------------------------------------------
// out[t] = sum_b partial_out[t][b] + bout
// ---------------------------------------------------------------------------
__global__ void out_reduce(const float* __restrict__ partial_out,
                           const float* __restrict__ bout,
                           float* __restrict__ out)
{
  int t = blockIdx.x;
  int lane = threadIdx.x;   // 64 threads
  float s = 0.f;
  #pragma unroll
  for (int q = 0; q < 4; ++q) s += partial_out[(int64_t)t * NCU + lane + 64 * q];
  s = wave_reduce(s);
  if (lane == 0) out[t] = s + bout[0];
}

extern "C" void kernel_launch(void* const* d_in, const int* in_sizes, int n_in,
                              void* d_out, int out_size, void* d_ws, size_t ws_size,
                              hipStream_t stream)
{
  const float* x    = (const float*)d_in[0];
  const float* Wih1 = (const float*)d_in[1];
  const float* Whh1 = (const float*)d_in[2];
  const float* b1   = (const float*)d_in[3];
  const float* Wih2 = (const float*)d_in[4];
  const float* Whh2 = (const float*)d_in[5];
  const float* b2   = (const float*)d_in[6];
  const float* Wout = (const float*)d_in[7];
  const float* bout = (const float*)d_in[8];
  float* out = (float*)d_out;

  char* ws = (char*)d_ws;
  size_t off = 0;
  auto take = [&](size_t bytes) -> char* {
    char* p = ws + off;
    off = (off + bytes + 255) & ~(size_t)255;
    return p;
  };
  uint32_t* lines    = (uint32_t*)take((size_t)4 * NCU * LINE_DW * 4);  // 64 KB
  float* partial_out = (float*)take((size_t)T_STEPS * NCU * 4);         // 2 MB

  if (off > ws_size) return;

  hipLaunchKernelGGL(prep_kernel, dim3(16), dim3(256), 0, stream, lines);

  void* args[] = { &x, &Wih1, &Whh1, &b1, &Wih2, &Whh2, &b2, &Wout,
                   &lines, &partial_out };
  (void)hipLaunchCooperativeKernel((void*)lstm_persist, dim3(NCU), dim3(TPB),
                                   args, 0, stream);

  hipLaunchKernelGGL(out_reduce, dim3(T_STEPS), dim3(64), 0, stream,
                     partial_out, bout, out);
}

// Round 10
// 7963.156 us; speedup vs baseline: 2.1612x; 1.3653x over previous
//
#include <hip/hip_runtime.h>
#include <stdint.h>

#define NCU 256
#define TPB 512
#define IN_DIM 1024
#define HID1   1024
#define HID2   2048
#define T_STEPS 2048

// LL exchange: line = {payload,tag} 8-B pairs, all within ONE 64-B sector.
// An 8-B store is a single transaction -> tag visible <=> payload visible;
// no vmcnt ack, no cross-line ordering assumption (r6 race impossible).
// lines1: 4 pairs (h1 units), lines2: 8 pairs (h2 units). 64-B stride.
#define LINE_DW 16

typedef float    f32x4 __attribute__((ext_vector_type(4)));
typedef uint32_t u32x4 __attribute__((ext_vector_type(4)));
typedef uint32_t u32x2 __attribute__((ext_vector_type(2)));
typedef __fp16   h16x2 __attribute__((ext_vector_type(2)));

__device__ __forceinline__ uint32_t pkh(float a, float b){
  h16x2 h = __builtin_amdgcn_cvt_pkrtz(a, b);
  uint32_t u; __builtin_memcpy(&u, &h, 4); return u;
}
__device__ __forceinline__ uint32_t pkhu(uint32_t a, uint32_t b){
  return pkh(__uint_as_float(a), __uint_as_float(b));
}

#if __has_builtin(__builtin_amdgcn_fdot2)
__device__ __forceinline__ float fdot2_(uint32_t w, uint32_t h, float c){
  h16x2 wf, hf; __builtin_memcpy(&wf, &w, 4); __builtin_memcpy(&hf, &h, 4);
  return __builtin_amdgcn_fdot2(wf, hf, c, false);
}
#else
__device__ __forceinline__ float fdot2_(uint32_t w, uint32_t h, float c){
  h16x2 wf, hf; __builtin_memcpy(&wf, &w, 4); __builtin_memcpy(&hf, &h, 4);
  c = fmaf((float)wf[0], (float)hf[0], c);
  return fmaf((float)wf[1], (float)hf[1], c);
}
#endif

__device__ __forceinline__ float dot16(u32x4 w, u32x4 h, float c){
  c = fdot2_(w[0], h[0], c); c = fdot2_(w[1], h[1], c);
  c = fdot2_(w[2], h[2], c); c = fdot2_(w[3], h[3], c);
  return c;
}

__device__ __forceinline__ float wave_reduce(float v){
  v += __shfl_xor(v, 32); v += __shfl_xor(v, 16); v += __shfl_xor(v, 8);
  v += __shfl_xor(v, 4);  v += __shfl_xor(v, 2);  v += __shfl_xor(v, 1);
  return v;
}

__device__ __forceinline__ float sigm_(float x){
  return __builtin_amdgcn_rcpf(1.f + __expf(-x));
}
__device__ __forceinline__ float tanh_(float x){
  float e = __expf(2.f * x);
  return (e - 1.f) * __builtin_amdgcn_rcpf(e + 1.f);
}

__global__ void prep_kernel(uint32_t* __restrict__ lines)
{
  int idx = blockIdx.x * blockDim.x + threadIdx.x;
  const int total = 2 * 4 * NCU * LINE_DW;
  for (int i = idx; i < total; i += gridDim.x * blockDim.x)
    __hip_atomic_store(lines + i, 0u, __ATOMIC_RELAXED, __HIP_MEMORY_SCOPE_AGENT);
}

// ---------------------------------------------------------------------------
// persistent 2-layer LSTM scan. 256 blocks (1/CU) x 512 threads.
// Block b owns layer1 units [4b,4b+4) and layer2 units [8b,8b+8).
// Iteration t: phaseA -> S1 -> {wave0: gates1+publish h1[t] | waves1-7:
// phaseB} -> S2 -> {wave0: gates2+publish h2[t-2]+partial | waves4-7:
// gather h1[t] (landed during phaseB) then h2[t-2]} -> S3.
// ---------------------------------------------------------------------------
__global__ __launch_bounds__(TPB, 1) void lstm_persist(
    const float* __restrict__ x,    const float* __restrict__ Wih1,
    const float* __restrict__ Whh1, const float* __restrict__ b1,
    const float* __restrict__ Wih2, const float* __restrict__ Whh2,
    const float* __restrict__ b2,   const float* __restrict__ Wout,
    uint32_t* __restrict__ lines,   float* __restrict__ partial_out)
{
  __shared__ u32x4 whh2_u4[32 * 256];   // 128 KiB f16 Whh2 slice (granules)
  __shared__ u32x4 h1g[2][128];         // h1 packed f16, double-buffered
  __shared__ u32x4 h2g[256];            // h2 packed f16
  __shared__ float gsum1[16], gx1v[16], gsum2[32], b2v[32];

  uint32_t* lines1 = lines;
  uint32_t* lines2 = lines + 4 * NCU * LINE_DW;

  const int b    = blockIdx.x;
  const int tid  = threadIdx.x;
  const int lane = tid & 63;
  const int wv   = tid >> 6;   // 8 waves

  // ---- init: stage Whh2 slice into LDS (fp32 -> f16 granules) ----
  for (int i = tid; i < 32 * 256; i += TPB) {
    int lr = i >> 8, u = i & 255;
    int g = lr >> 3, uu2 = lr & 7;
    const f32x4* s4 = (const f32x4*)(Whh2 + (int64_t)(g * HID2 + 8 * b + uu2) * HID2);
    f32x4 lo = s4[2 * u], hi = s4[2 * u + 1];
    u32x4 wv4;
    wv4[0] = pkh(lo[0], lo[1]); wv4[1] = pkh(lo[2], lo[3]);
    wv4[2] = pkh(hi[0], hi[1]); wv4[3] = pkh(hi[2], hi[3]);
    whh2_u4[i] = wv4;
  }

  // ---- Whh1 slice in registers (f16 granules, 2 rows/wave, 8 waves) ----
  u32x4 w1g[2][2];
  int rows1[2];
  #pragma unroll
  for (int rr = 0; rr < 2; ++rr) {
    int lr1 = wv * 2 + rr;
    int g = lr1 >> 2, uu = lr1 & 3;
    int row = g * HID1 + 4 * b + uu;
    rows1[rr] = row;
    const f32x4* s4 = (const f32x4*)(Whh1 + (int64_t)row * IN_DIM);
    #pragma unroll
    for (int q = 0; q < 2; ++q) {
      int u = lane + 64 * q;
      f32x4 lo = s4[2 * u], hi = s4[2 * u + 1];
      u32x4 wv4;
      wv4[0] = pkh(lo[0], lo[1]); wv4[1] = pkh(lo[2], lo[3]);
      wv4[2] = pkh(hi[0], hi[1]); wv4[3] = pkh(hi[2], hi[3]);
      w1g[rr][q] = wv4;
    }
  }

  // ---- Wih2 slice in registers: waves 1..7, rows lr = (wv-1)+7k, k<5 ----
  u32x4 wi_reg[5][2];
  #pragma unroll
  for (int k = 0; k < 5; ++k) {
    int lr = (wv - 1) + 7 * k;
    if (wv >= 1 && lr < 32) {
      int g = lr >> 3, uu = lr & 7;
      const f32x4* s4 = (const f32x4*)(Wih2 + (int64_t)(g * HID2 + 8 * b + uu) * IN_DIM);
      #pragma unroll
      for (int q = 0; q < 2; ++q) {
        int u = lane + 64 * q;
        f32x4 lo = s4[2 * u], hi = s4[2 * u + 1];
        u32x4 wv4;
        wv4[0] = pkh(lo[0], lo[1]); wv4[1] = pkh(lo[2], lo[3]);
        wv4[2] = pkh(hi[0], hi[1]); wv4[3] = pkh(hi[2], hi[3]);
        wi_reg[k][q] = wv4;
      }
    }
  }

  // ---- gx1 = Wih1 @ x + b1 (constant over t; fp32, init-only) ----
  #pragma unroll
  for (int rr = 0; rr < 2; ++rr) {
    int row = rows1[rr];
    float s = 0.f;
    #pragma unroll
    for (int j = 0; j < 16; ++j)
      s += Wih1[(int64_t)row * IN_DIM + lane + 64 * j] * x[lane + 64 * j];
    s = wave_reduce(s);
    if (lane == 0) gx1v[wv * 2 + rr] = s + b1[row];
  }
  if (tid < 32) { int g = tid >> 3, uu = tid & 7; b2v[tid] = b2[g * HID2 + 8 * b + uu]; }
  {
    uint32_t* p1 = (uint32_t*)h1g;
    uint32_t* p2 = (uint32_t*)h2g;
    for (int i = tid; i < 2 * 128 * 4; i += TPB) p1[i] = 0u;
    for (int i = tid; i < 256 * 4;     i += TPB) p2[i] = 0u;
  }

  const float woutreg = Wout[8 * b + (lane & 7)];
  float c1reg = 0.f, c2reg = 0.f;
  __syncthreads();

  // ---- time loop ----
  for (int t = 0; t < T_STEPS + 2; ++t) {
    // ======== segment 1: phase A (all 8 waves) ========
    if (t < T_STEPS) {
      const u32x4* h1A = h1g[(t + 1) & 1];
      u32x4 ha0 = h1A[lane], ha1 = h1A[64 + lane];
      #pragma unroll
      for (int rr = 0; rr < 2; ++rr) {
        float s = dot16(w1g[rr][0], ha0, 0.f);
        s = dot16(w1g[rr][1], ha1, s);
        s = wave_reduce(s);
        if (lane == 0) gsum1[wv * 2 + rr] = s;
      }
    }
    __syncthreads();   // S1: gsum1 ready

    // ======== segment 2: wave0 gates1+publish h1 | waves1-7 phase B ========
    if (wv == 0) {
      if (t < T_STEPS) {
        const int u1 = lane & 3;
        float gi = sigm_(gsum1[u1]      + gx1v[u1]);
        float gf = sigm_(gsum1[4 + u1]  + gx1v[4 + u1]);
        float gg = tanh_(gsum1[8 + u1]  + gx1v[8 + u1]);
        float go = sigm_(gsum1[12 + u1] + gx1v[12 + u1]);
        c1reg = gf * c1reg + gi * gg;
        float h1v = go * tanh_(c1reg);         // unit (lane&3)
        if (lane < 4) {                        // LL pair store, fire-and-forget
          uint32_t* p = lines1 + ((size_t)(t & 3) * NCU + b) * LINE_DW + 2 * lane;
          u32x2 st; st[0] = __float_as_uint(h1v); st[1] = (uint32_t)(t + 1);
          asm volatile("global_store_dwordx2 %0, %1, off sc0 sc1"
                       :: "v"(p), "v"(st) : "memory");
        }
      }
    } else if (t >= 2) {
      const u32x4* h1B = h1g[t & 1];
      u32x4 x1a = h1B[lane], x1b = h1B[64 + lane];
      u32x4 x20 = h2g[lane],       x21 = h2g[64 + lane];
      u32x4 x22 = h2g[128 + lane], x23 = h2g[192 + lane];
      #pragma unroll
      for (int k = 0; k < 5; ++k) {
        const int lr = (wv - 1) + 7 * k;
        if (lr < 32) {
          float s = dot16(wi_reg[k][0], x1a, 0.f);
          s = dot16(wi_reg[k][1], x1b, s);
          s = dot16(whh2_u4[lr * 256 + lane],       x20, s);
          s = dot16(whh2_u4[lr * 256 + 64 + lane],  x21, s);
          s = dot16(whh2_u4[lr * 256 + 128 + lane], x22, s);
          s = dot16(whh2_u4[lr * 256 + 192 + lane], x23, s);
          s = wave_reduce(s);
          if (lane == 0) gsum2[lr] = s;
        }
      }
    }
    __syncthreads();   // S2: gsum2 ready; h1 lines in flight since ~S1+gates

    // ======== segment 3: wave0 gates2+publish h2+partial | waves4-7 gather ==
    if (wv == 0 && t >= 2) {
      const int u2 = lane & 7;
      float gi = sigm_(gsum2[u2]      + b2v[u2]);
      float gf = sigm_(gsum2[8 + u2]  + b2v[8 + u2]);
      float gg = tanh_(gsum2[16 + u2] + b2v[16 + u2]);
      float go = sigm_(gsum2[24 + u2] + b2v[24 + u2]);
      c2reg = gf * c2reg + gi * gg;
      float h2v = go * tanh_(c2reg);           // unit (lane&7)
      if (t <= T_STEPS && lane < 8) {          // LL pair store
        uint32_t* p = lines2 + ((size_t)(t & 3) * NCU + b) * LINE_DW + 2 * lane;
        u32x2 st; st[0] = __float_as_uint(h2v); st[1] = (uint32_t)(t + 1);
        asm volatile("global_store_dwordx2 %0, %1, off sc0 sc1"
                     :: "v"(p), "v"(st) : "memory");
      }
      float contrib = (lane < 8) ? h2v * woutreg : 0.f;
      float po = wave_reduce(contrib);
      if (lane == 0) partial_out[(int64_t)(t - 2) * NCU + b] = po;
    }
    if (wv >= 4) {
      const int j = tid - NCU;
      const uint32_t tg = (uint32_t)(t + 1);
      if (t < T_STEPS) {
        // gather h1[t]: 2 dwordx4 burst, tags at odd dwords
        const uint32_t* l1 = lines1 + ((size_t)(t & 3) * NCU + j) * LINE_DW;
        for (;;) {
          u32x4 d0, d1;
          asm volatile("global_load_dwordx4 %0, %1, off sc0 sc1"
                       : "=&v"(d0) : "v"(l1));
          asm volatile("global_load_dwordx4 %0, %1, off offset:16 sc0 sc1"
                       : "=&v"(d1) : "v"(l1));
          asm volatile("s_waitcnt vmcnt(0)" ::: "memory");
          if (d0[1] == tg && d0[3] == tg && d1[1] == tg && d1[3] == tg) {
            u32x2 hp; hp[0] = pkhu(d0[0], d0[2]); hp[1] = pkhu(d1[0], d1[2]);
            ((u32x2*)h1g[t & 1])[j] = hp;      // becomes h1[t]
            break;
          }
          __builtin_amdgcn_s_sleep(1);
        }
      }
      if (t >= 2 && t <= T_STEPS) {
        // gather h2[t-2]: 4 dwordx4 burst
        const uint32_t* l2 = lines2 + ((size_t)(t & 3) * NCU + j) * LINE_DW;
        for (;;) {
          u32x4 d0, d1, d2, d3;
          asm volatile("global_load_dwordx4 %0, %1, off sc0 sc1"
                       : "=&v"(d0) : "v"(l2));
          asm volatile("global_load_dwordx4 %0, %1, off offset:16 sc0 sc1"
                       : "=&v"(d1) : "v"(l2));
          asm volatile("global_load_dwordx4 %0, %1, off offset:32 sc0 sc1"
                       : "=&v"(d2) : "v"(l2));
          asm volatile("global_load_dwordx4 %0, %1, off offset:48 sc0 sc1"
                       : "=&v"(d3) : "v"(l2));
          asm volatile("s_waitcnt vmcnt(0)" ::: "memory");
          if (d0[1] == tg && d0[3] == tg && d1[1] == tg && d1[3] == tg &&
              d2[1] == tg && d2[3] == tg && d3[1] == tg && d3[3] == tg) {
            u32x4 hp;
            hp[0] = pkhu(d0[0], d0[2]); hp[1] = pkhu(d1[0], d1[2]);
            hp[2] = pkhu(d2[0], d2[2]); hp[3] = pkhu(d3[0], d3[2]);
            h2g[j] = hp;                       // becomes h2[t-2]
            break;
          }
          __builtin_amdgcn_s_sleep(1);
        }
      }
    }
    __syncthreads();   // S3
  }
}

// ---------------------------------------------------------------------------
// out[t] = sum_b partial_out[t][b] + bout
// ---------------------------------------------------------------------------
__global__ void out_reduce(const float* __restrict__ partial_out,
                           const float* __restrict__ bout,
                           float* __restrict__ out)
{
  int t = blockIdx.x;
  int lane = threadIdx.x;   // 64 threads
  float s = 0.f;
  #pragma unroll
  for (int q = 0; q < 4; ++q) s += partial_out[(int64_t)t * NCU + lane + 64 * q];
  s = wave_reduce(s);
  if (lane == 0) out[t] = s + bout[0];
}

extern "C" void kernel_launch(void* const* d_in, const int* in_sizes, int n_in,
                              void* d_out, int out_size, void* d_ws, size_t ws_size,
                              hipStream_t stream)
{
  const float* x    = (const float*)d_in[0];
  const float* Wih1 = (const float*)d_in[1];
  const float* Whh1 = (const float*)d_in[2];
  const float* b1   = (const float*)d_in[3];
  const float* Wih2 = (const float*)d_in[4];
  const float* Whh2 = (const float*)d_in[5];
  const float* b2   = (const float*)d_in[6];
  const float* Wout = (const float*)d_in[7];
  const float* bout = (const float*)d_in[8];
  float* out = (float*)d_out;

  char* ws = (char*)d_ws;
  size_t off = 0;
  auto take = [&](size_t bytes) -> char* {
    char* p = ws + off;
    off = (off + bytes + 255) & ~(size_t)255;
    return p;
  };
  uint32_t* lines    = (uint32_t*)take((size_t)2 * 4 * NCU * LINE_DW * 4); // 128 KB
  float* partial_out = (float*)take((size_t)T_STEPS * NCU * 4);            // 2 MB

  if (off > ws_size) return;

  hipLaunchKernelGGL(prep_kernel, dim3(32), dim3(256), 0, stream, lines);

  void* args[] = { &x, &Wih1, &Whh1, &b1, &Wih2, &Whh2, &b2, &Wout,
                   &lines, &partial_out };
  (void)hipLaunchCooperativeKernel((void*)lstm_persist, dim3(NCU), dim3(TPB),
                                   args, 0, stream);

  hipLaunchKernelGGL(out_reduce, dim3(T_STEPS), dim3(64), 0, stream,
                     partial_out, bout, out);
}